// Round 21
// baseline (189.324 us; speedup 1.0000x reference)
//
#include <hip/hip_runtime.h>

typedef __attribute__((ext_vector_type(8))) short s16x8;
typedef __attribute__((ext_vector_type(4))) float f32x4;
typedef __attribute__((ext_vector_type(16))) float f32x16;
typedef __attribute__((ext_vector_type(4))) uint u32x4;
typedef __attribute__((ext_vector_type(2))) uint u32x2;
typedef __attribute__((ext_vector_type(2))) long s64x2;
typedef __attribute__((ext_vector_type(8))) int i32x8;
typedef unsigned char u8;

#define MFMA16(a, b, c) __builtin_amdgcn_mfma_f32_16x16x32_bf16((a), (b), (c), 0, 0, 0)
#define MFMAF8(a, b, c) __builtin_amdgcn_mfma_f32_32x32x16_fp8_fp8((a), (b), (c), 0, 0, 0)
// MX-scaled fp8 K=64; fmt 0,0 = e4m3/e4m3; scale bytes 0x7F = e8m0 1.0
#define MFMAMX(a, b, c) \
  __builtin_amdgcn_mfma_scale_f32_32x32x64_f8f6f4((a), (b), (c), 0, 0, 0, 0x7F7F7F7F, 0, 0x7F7F7F7F)

__device__ __forceinline__ ushort f2bf(float f) {
  uint u = __builtin_bit_cast(uint, f);
  u = (u + 0x7fffu + ((u >> 16) & 1u)) >> 16;
  return (ushort)u;
}
__device__ __forceinline__ float max3f(float a, float b, float c) {
  return fmaxf(fmaxf(a, b), c);   // clang fuses to v_max3_f32
}

// ---------------- GN stats (512 blocks) + weight conversion (64 blocks) ----------
__global__ __launch_bounds__(256) void gn_stats_cvt_kernel(
    const float* __restrict__ x, float2* __restrict__ partial,
    const float* __restrict__ wq, const float* __restrict__ wk,
    const float* __restrict__ wv, const float* __restrict__ wp,
    u8* __restrict__ wcat8, ushort* __restrict__ wpb,
    const float* __restrict__ bq, const float* __restrict__ bk,
    const float* __restrict__ bv, float* __restrict__ bcat) {
  if (blockIdx.x >= 512) {
    int i = (blockIdx.x - 512) * 256 + threadIdx.x;  // [0,16384) float4
    const float4* s[3] = {(const float4*)wq, (const float4*)wk, (const float4*)wv};
#pragma unroll
    for (int m = 0; m < 3; ++m) {
      float4 v = s[m][i];
      uint u = (uint)__builtin_amdgcn_cvt_pk_fp8_f32(v.x, v.y, 0, false);
      u = (uint)__builtin_amdgcn_cvt_pk_fp8_f32(v.z, v.w, (int)u, true);
      ((uint*)wcat8)[m * 16384 + i] = u;
    }
    {
      float4 v = ((const float4*)wp)[i];
      uint lo = (uint)f2bf(v.x) | ((uint)f2bf(v.y) << 16);
      uint hi = (uint)f2bf(v.z) | ((uint)f2bf(v.w) << 16);
      *(uint2*)(wpb + (size_t)i * 4) = make_uint2(lo, hi);
    }
    if (blockIdx.x == 512) {
      int t = threadIdx.x;
      bcat[t] = bq[t];
      bcat[256 + t] = bk[t];
      bcat[512 + t] = bv[t];
    }
    return;
  }
  int bid = blockIdx.x;
  int b = bid >> 6, g = (bid >> 3) & 7, sl = bid & 7;
  const float4* src = (const float4*)(x + ((size_t)b * 256 + g * 32) * 4096) + sl * 4096;
  float s = 0.f, ss = 0.f;
#pragma unroll 4
  for (int i = threadIdx.x; i < 4096; i += 256) {
    float4 v = src[i];
    s += v.x + v.y + v.z + v.w;
    ss += v.x * v.x + v.y * v.y + v.z * v.z + v.w * v.w;
  }
#pragma unroll
  for (int off = 32; off; off >>= 1) {
    s += __shfl_down(s, off);
    ss += __shfl_down(ss, off);
  }
  __shared__ float ps[4], pss[4];
  int w = threadIdx.x >> 6, lane = threadIdx.x & 63;
  if (lane == 0) { ps[w] = s; pss[w] = ss; }
  __syncthreads();
  if (threadIdx.x == 0) {
    float2 r;
    r.x = ps[0] + ps[1] + ps[2] + ps[3];
    r.y = pss[0] + pss[1] + pss[2] + pss[3];
    partial[bid] = r;
  }
}

// ---------------- GN apply + transpose -> fp8 y (finalizes stats in-block) --------
__global__ __launch_bounds__(256) void gn_apply_kernel(
    const float* __restrict__ x, const float2* __restrict__ partial,
    const float* __restrict__ gw, const float* __restrict__ gb,
    u8* __restrict__ y8) {
  int bid = blockIdx.x;
  int b = bid >> 8;
  int rem = bid & 255;
  int ct = rem >> 6, nt = rem & 63;   // 64-channel tile = groups 2ct, 2ct+1
  int t = threadIdx.x;
  __shared__ float xs[64][65];
  __shared__ float smu2[2], srs2[2];
  if (t < 2) {
    float S = 0.f, SS = 0.f;
#pragma unroll
    for (int i = 0; i < 8; ++i) {
      float2 p = partial[(b << 6) | ((2 * ct + t) << 3) | i];
      S += p.x;
      SS += p.y;
    }
    float mu = S * (1.f / 131072.f);
    float var = SS * (1.f / 131072.f) - mu * mu;
    smu2[t] = mu;
    srs2[t] = rsqrtf(var + 1e-5f);
  }
  const float* xb = x + ((size_t)b * 256 + ct * 64) * 4096 + nt * 64;
  {
    int r = t >> 2, q = t & 3;
    const float4* src = (const float4*)(xb + (size_t)r * 4096 + q * 16);
#pragma unroll
    for (int i = 0; i < 4; ++i) {
      float4 v = src[i];
      xs[r][q * 16 + i * 4 + 0] = v.x;
      xs[r][q * 16 + i * 4 + 1] = v.y;
      xs[r][q * 16 + i * 4 + 2] = v.z;
      xs[r][q * 16 + i * 4 + 3] = v.w;
    }
  }
  __syncthreads();
  {
    int nr = t >> 2, q = t & 3;
    int c0 = q * 16;
    float vv[16];
#pragma unroll
    for (int i = 0; i < 16; ++i) {
      int ci = c0 + i;                  // 0..63 within tile
      int ch = ct * 64 + ci;
      int gsel = ci >> 5;
      float sc = gw[ch] * srs2[gsel];
      float sh = gb[ch] - smu2[gsel] * sc;
      vv[i] = xs[ci][nr] * sc + sh;
    }
    uint pw[4];
#pragma unroll
    for (int j = 0; j < 4; ++j) {
      uint u = (uint)__builtin_amdgcn_cvt_pk_fp8_f32(vv[4 * j], vv[4 * j + 1], 0, false);
      u = (uint)__builtin_amdgcn_cvt_pk_fp8_f32(vv[4 * j + 2], vv[4 * j + 3], (int)u, true);
      pw[j] = u;
    }
    u8* dst = y8 + ((size_t)(b * 4096 + nt * 64 + nr)) * 256 + ct * 64 + c0;
    u32x4 ov = {pw[0], pw[1], pw[2], pw[3]};
    *(u32x4*)dst = ov;
  }
}

// ---------------- QKV GEMM v4: fp8 MX, single-stage 64KB LDS, 2 blocks/CU --------
// C[4096][768] = y8 . wcat8^T + bcat; outputs routed to qb8/kb8/vtb8 (fp8).
__global__ __launch_bounds__(256) void gemm_qkv_kernel(
    const u8* __restrict__ A, const u8* __restrict__ B,
    const float* __restrict__ bias, u8* __restrict__ Cq) {
  int tm = blockIdx.x & 31, tn = blockIdx.x >> 5;   // 32 M-tiles x 6 N-tiles
  int bb = blockIdx.y;
  const u8* Ab = A + (size_t)bb * (4096 * 256) + (size_t)tm * 128 * 256;
  const u8* Bb = B + (size_t)tn * 128 * 256;

  __shared__ u8 As[32768];   // [128][256] fp8, XOR-swizzled (P = L ^ ((L>>4)&7))
  __shared__ u8 Bs[32768];

  int t = threadIdx.x, lane = t & 63, w = t >> 6;
  int wr = w >> 1, wc = w & 1, lq = lane & 31, lh = lane >> 5;

  f32x16 acc[2][2];
#pragma unroll
  for (int i = 0; i < 2; ++i)
#pragma unroll
    for (int j = 0; j < 2; ++j) acc[i][j] = (f32x16)(0.f);

  // stage full tiles: 8+8 DMA loads per thread
#pragma unroll
  for (int i = 0; i < 8; ++i) {
    int bu = i * 256 + w * 64;          // wave-uniform base unit (16B units)
    int Pu = bu + lane;                 // 0..2047
    int Lu = Pu ^ ((Pu >> 4) & 7);      // logical unit (same involution as attn K)
    int off = (Lu >> 4) * 256 + (Lu & 15) * 16;
    __builtin_amdgcn_global_load_lds(
        (const __attribute__((address_space(1))) uint*)(Ab + off),
        (__attribute__((address_space(3))) uint*)(As + bu * 16), 16, 0, 0);
    __builtin_amdgcn_global_load_lds(
        (const __attribute__((address_space(1))) uint*)(Bb + off),
        (__attribute__((address_space(3))) uint*)(Bs + bu * 16), 16, 0, 0);
  }
  asm volatile("s_waitcnt vmcnt(0)" ::: "memory");
  __builtin_amdgcn_s_barrier();

  // 16 MX MFMAs per wave (4 k-steps x 2x2 frags)
#pragma unroll
  for (int ks = 0; ks < 4; ++ks) {
    i32x8 af[2], bf[2];
#pragma unroll
    for (int mt = 0; mt < 2; ++mt) {
      int ra = wr * 64 + mt * 32 + lq;
      int u0 = (ks * 4 + lh * 2) ^ (ra & 7);
      int u1 = (ks * 4 + lh * 2 + 1) ^ (ra & 7);
      u32x4 lo = *(const u32x4*)(As + ra * 256 + u0 * 16);
      u32x4 hi = *(const u32x4*)(As + ra * 256 + u1 * 16);
      af[mt] = i32x8{(int)lo[0], (int)lo[1], (int)lo[2], (int)lo[3],
                     (int)hi[0], (int)hi[1], (int)hi[2], (int)hi[3]};
    }
#pragma unroll
    for (int nt = 0; nt < 2; ++nt) {
      int rb = wc * 64 + nt * 32 + lq;
      int u0 = (ks * 4 + lh * 2) ^ (rb & 7);
      int u1 = (ks * 4 + lh * 2 + 1) ^ (rb & 7);
      u32x4 lo = *(const u32x4*)(Bs + rb * 256 + u0 * 16);
      u32x4 hi = *(const u32x4*)(Bs + rb * 256 + u1 * 16);
      bf[nt] = i32x8{(int)lo[0], (int)lo[1], (int)lo[2], (int)lo[3],
                     (int)hi[0], (int)hi[1], (int)hi[2], (int)hi[3]};
    }
#pragma unroll
    for (int mt = 0; mt < 2; ++mt)
#pragma unroll
      for (int nt = 0; nt < 2; ++nt)
        acc[mt][nt] = MFMAMX(af[mt], bf[nt], acc[mt][nt]);
  }

  // epilogue: route fp8 bytes to qb8 / kb8(+16MB) / vtb8(+32MB, kv-perm on row)
  u8* Cb = Cq + (size_t)bb * (4096 * 256);
#pragma unroll
  for (int mt = 0; mt < 2; ++mt) {
#pragma unroll
    for (int nt = 0; nt < 2; ++nt) {
#pragma unroll
      for (int r = 0; r < 16; ++r) {
        int row = tm * 128 + wr * 64 + mt * 32 + (r & 3) + 8 * (r >> 2) + 4 * lh;
        int col = tn * 128 + wc * 64 + nt * 32 + lq;
        float v = acc[mt][nt][r] + bias[col];
        uint pk8 = (uint)__builtin_amdgcn_cvt_pk_fp8_f32(v, v, 0, false);
        if (col < 512) {
          u8* C = Cb + ((col >= 256) ? 16777216 : 0);
          C[(size_t)row * 256 + (col & 255)] = (u8)(pk8 & 0xff);
        } else {
          int rr = row & 31;
          int pr = (row & ~31) |
                   ((rr & 7) | (((rr >> 4) & 1) << 3) | (((rr >> 3) & 1) << 4));
          u8* C = Cb + 33554432;
          C[(size_t)(col - 512) * 4096 + pr] = (u8)(pk8 & 0xff);
        }
      }
    }
  }
}

// ---------------- proj GEMM with fused kv-half merge ----------------
__global__ __launch_bounds__(256) void gemm_proj_kernel(
    const ushort* __restrict__ A, const ushort* __restrict__ P0,
    const ushort* __restrict__ P1, const float* __restrict__ mlb,
    const float* __restrict__ bias, const float* __restrict__ resid,
    float* __restrict__ Cout) {
  const size_t MAT = 4096 * 256;
  int tm = blockIdx.x & 1, tn = blockIdx.x >> 1;   // 2 x 32 tiles
  int bb = blockIdx.y;
  const ushort* Ab = A + (size_t)tm * 128 * 256;
  const ushort* P0b = P0 + (size_t)bb * MAT + (size_t)tn * 128 * 256;
  const ushort* P1b = P1 + (size_t)bb * MAT + (size_t)tn * 128 * 256;
  const int mlbase = bb * 4096 + tn * 128;

  __shared__ ushort As[2][8192];
  __shared__ ushort Bs[2][8192];

  int t = threadIdx.x, lane = t & 63, w = t >> 6;
  int wr = w >> 1, wc = w & 1, lq = lane & 15, lg = lane >> 4;

  f32x4 acc[4][4];
#pragma unroll
  for (int i = 0; i < 4; ++i)
#pragma unroll
    for (int j = 0; j < 4; ++j) acc[i][j] = f32x4{0.f, 0.f, 0.f, 0.f};

  u32x4 rb0[4], rb1[4];
  float rw0[4], rw1[4];

  auto issueA = [&](int kb, int db) {
#pragma unroll
    for (int i = 0; i < 4; ++i) {
      int bu = i * 256 + w * 64;
      int u = bu + lane;
      int row = u >> 3, c = u & 7;
      int cl = c ^ (row & 7);
      const ushort* sa = Ab + (size_t)row * 256 + kb * 64 + cl * 8;
      __builtin_amdgcn_global_load_lds(
          (const __attribute__((address_space(1))) uint*)sa,
          (__attribute__((address_space(3))) uint*)(&As[db][0] + bu * 8), 16, 0, 0);
    }
  };
  auto loadB = [&](int kb) {
#pragma unroll
    for (int i = 0; i < 4; ++i) {
      int bu = i * 256 + w * 64;
      int u = bu + lane;
      int row = u >> 3, c = u & 7;
      int cl = c ^ (row & 7);
      rb0[i] = *(const u32x4*)(P0b + (size_t)row * 256 + kb * 64 + cl * 8);
      rb1[i] = *(const u32x4*)(P1b + (size_t)row * 256 + kb * 64 + cl * 8);
      int gr = mlbase + row;
      float m0 = mlb[gr], m1 = mlb[32768 + gr];
      float l0 = mlb[65536 + gr], l1 = mlb[98304 + gr];
      float M = fmaxf(m0, m1);
      float e0 = __builtin_exp2f(m0 - M), e1 = __builtin_exp2f(m1 - M);
      float inv = 1.f / (l0 * e0 + l1 * e1);
      rw0[i] = e0 * inv;
      rw1[i] = e1 * inv;
    }
  };
  auto writeB = [&](int db) {
#pragma unroll
    for (int i = 0; i < 4; ++i) {
      int bu = i * 256 + w * 64;
      uint outw[4];
#pragma unroll
      for (int j = 0; j < 4; ++j) {
        float alo = __builtin_bit_cast(float, rb0[i][j] << 16);
        float ahi = __builtin_bit_cast(float, rb0[i][j] & 0xffff0000u);
        float blo = __builtin_bit_cast(float, rb1[i][j] << 16);
        float bhi = __builtin_bit_cast(float, rb1[i][j] & 0xffff0000u);
        float flo = alo * rw0[i] + blo * rw1[i];
        float fhi = ahi * rw0[i] + bhi * rw1[i];
        asm("v_cvt_pk_bf16_f32 %0, %1, %2" : "=v"(outw[j]) : "v"(flo), "v"(fhi));
      }
      u32x4 ov = {outw[0], outw[1], outw[2], outw[3]};
      *(u32x4*)&Bs[db][(size_t)(bu + lane) * 8] = ov;
    }
  };

  issueA(0, 0);
  loadB(0);
  writeB(0);
  asm volatile("s_waitcnt vmcnt(0) lgkmcnt(0)" ::: "memory");
  __builtin_amdgcn_s_barrier();

#pragma unroll
  for (int kb = 0; kb < 4; ++kb) {
    const int db = kb & 1;
    if (kb < 3) {
      issueA(kb + 1, db ^ 1);
      loadB(kb + 1);                    // loads in flight across compute
    }
    const ushort* Abf = &As[db][0];
    const ushort* Bbf = &Bs[db][0];
#pragma unroll
    for (int ks = 0; ks < 2; ++ks) {
      s16x8 af[4], bf[4];
#pragma unroll
      for (int mt = 0; mt < 4; ++mt) {
        int row = wr * 64 + mt * 16 + lq;
        af[mt] = *(const s16x8*)&Abf[row * 64 + (((ks * 4 + lg) ^ (row & 7)) << 3)];
      }
#pragma unroll
      for (int nt = 0; nt < 4; ++nt) {
        int row = wc * 64 + nt * 16 + lq;
        bf[nt] = *(const s16x8*)&Bbf[row * 64 + (((ks * 4 + lg) ^ (row & 7)) << 3)];
      }
#pragma unroll
      for (int mt = 0; mt < 4; ++mt)
#pragma unroll
        for (int nt = 0; nt < 4; ++nt)
          acc[mt][nt] = MFMA16(af[mt], bf[nt], acc[mt][nt]);
    }
    if (kb < 3) writeB(db ^ 1);
    asm volatile("s_waitcnt vmcnt(0) lgkmcnt(0)" ::: "memory");
    __builtin_amdgcn_s_barrier();
  }

  int mBase = tm * 128 + wr * 64;
  int nBase = tn * 128 + wc * 64;
#pragma unroll
  for (int mt = 0; mt < 4; ++mt) {
#pragma unroll
    for (int nt = 0; nt < 4; ++nt) {
#pragma unroll
      for (int r = 0; r < 4; ++r) {
        int row = mBase + mt * 16 + lg * 4 + r;
        int col = nBase + nt * 16 + lq;
        size_t idx = (size_t)bb * MAT + (size_t)row * 4096 + col;
        Cout[idx] = acc[mt][nt][r] + bias[row] + resid[idx];
      }
    }
  }
}

// ---------------- Flash attention v13: KVBLK=64 super-iters (2 sub-passes) -------
// Grid 512 = 8 batch x 32 qtiles(128 rows) x 2 kv-halves; 256 thr = 4 waves.
// Per super-iter: stage TWO 32-kv chunks (32KB buf, dbuf 64KB), ONE barrier pair,
// sub-loop (#pragma unroll 1 caps reg pressure) runs the proven body twice.
__global__ __launch_bounds__(256, 2) void attn13_kernel(
    const u8* __restrict__ q, const u8* __restrict__ k,
    const u8* __restrict__ vT, ushort* __restrict__ pb0,
    ushort* __restrict__ pb1, float* __restrict__ mlbuf) {
  const int bb = blockIdx.x & 7;          // batch -> XCD pinning
  const int rem = blockIdx.x >> 3;        // 0..63
  const int qt = rem & 31;                // 32 qtiles x 128 rows
  const int half = rem >> 5;              // kv half
  const int t = threadIdx.x, w = t >> 6, lane = t & 63;
  const int lq = lane & 31, lh = lane >> 5;

  __shared__ u8 Lf[65536];   // 2 bufs x (2 chunks x (K 8KB + V 8KB)); epilogue 64KB

  // Q fragments for MX QK: frag ks holds channels ks*64 + lh*32 .. +31 (32B)
  const int qrow = bb * 4096 + qt * 128 + w * 32 + lq;
  i32x8 qf8[4];
  {
    const u8* qp = q + (size_t)qrow * 256 + lh * 32;
#pragma unroll
    for (int ks = 0; ks < 4; ++ks) {
      u32x4 lo = *(const u32x4*)(qp + ks * 64);
      u32x4 hi = *(const u32x4*)(qp + ks * 64 + 16);
      qf8[ks] = i32x8{(int)lo[0], (int)lo[1], (int)lo[2], (int)lo[3],
                      (int)hi[0], (int)hi[1], (int)hi[2], (int)hi[3]};
    }
  }
  f32x16 oacc[8];
#pragma unroll
  for (int i = 0; i < 8; ++i) oacc[i] = (f32x16)(0.f);
  float mrun = -3e38f, lrun = 0.f;        // exp2 (log2) domain
  const float cs = 0.0625f * 1.44269504f; // scale * log2(e)

  // precomputed, chunk-invariant staging source pointers (incremented per chunk)
  const u8* ksrc0;
  const u8* ksrc1;
  const u8* vsrc0;
  const u8* vsrc1;
  {
    const u8* kb0 = k + (size_t)bb * (4096 * 256) + (size_t)(half * 64) * (32 * 256);
    const u8* vb0 = vT + (size_t)bb * (4096 * 256) + (size_t)(half * 64) * 32;
    int bu0 = w * 128, bu1 = w * 128 + 64;
    int P0 = bu0 + lane, P1 = bu1 + lane;
    int L0 = P0 ^ ((P0 >> 4) & 7), L1 = P1 ^ ((P1 >> 4) & 7);
    ksrc0 = kb0 + (L0 >> 4) * 256 + (L0 & 15) * 16;
    ksrc1 = kb0 + (L1 >> 4) * 256 + (L1 & 15) * 16;
    int M0 = P0 ^ ((P0 >> 3) & 7), M1 = P1 ^ ((P1 >> 3) & 7);
    vsrc0 = vb0 + (size_t)(M0 >> 1) * 4096 + (M0 & 1) * 16;
    vsrc1 = vb0 + (size_t)(M1 >> 1) * 4096 + (M1 & 1) * 16;
  }
  const int kdst0 = w * 128 * 16, kdst1 = (w * 128 + 64) * 16;

  // stage chunk `ci` (32 kv) at Lf byte offset `dst` (K 8KB + V 8KB)
  auto stage = [&](int ci, int dst) {
    u8* base = Lf + dst;
    size_t ko = (size_t)ci * 8192;      // 32*256 bytes per chunk along kv
    size_t vo = (size_t)ci * 32;        // 32 bytes per chunk along n
    __builtin_amdgcn_global_load_lds(
        (const __attribute__((address_space(1))) uint*)(ksrc0 + ko),
        (__attribute__((address_space(3))) uint*)(base + kdst0), 16, 0, 0);
    __builtin_amdgcn_global_load_lds(
        (const __attribute__((address_space(1))) uint*)(ksrc1 + ko),
        (__attribute__((address_space(3))) uint*)(base + kdst1), 16, 0, 0);
    __builtin_amdgcn_global_load_lds(
        (const __attribute__((address_space(1))) uint*)(vsrc0 + vo),
        (__attribute__((address_space(3))) uint*)(base + 8192 + kdst0), 16, 0, 0);
    __builtin_amdgcn_global_load_lds(
        (const __attribute__((address_space(1))) uint*)(vsrc1 + vo),
        (__attribute__((address_space(3))) uint*)(base + 8192 + kdst1), 16, 0, 0);
  };

  stage(0, 0);
  stage(1, 16384);

#pragma unroll 1
  for (int j = 0; j < 32; ++j) {
    if (j < 31) {
      int nb = ((j + 1) & 1) * 32768;
      stage(2 * j + 2, nb);
      stage(2 * j + 3, nb + 16384);
      asm volatile("s_waitcnt vmcnt(8)" ::: "memory");
    } else {
      asm volatile("s_waitcnt vmcnt(0)" ::: "memory");
    }
    __builtin_amdgcn_s_barrier();

#pragma unroll 1
    for (int s = 0; s < 2; ++s) {
      const u8* Kbf = Lf + (j & 1) * 32768 + s * 16384;
      const u8* Vbf = Kbf + 8192;

      // ---- QK^T: 4 MX-scaled MFMAs (K=64 each), single chain ----
      __builtin_amdgcn_s_setprio(1);
      f32x16 sA = (f32x16)(0.f);
#pragma unroll
      for (int ks = 0; ks < 4; ++ks) {
        int u0 = (lq * 16 + ks * 4 + lh * 2) ^ (lq & 7);
        int u1 = (lq * 16 + ks * 4 + lh * 2 + 1) ^ (lq & 7);
        u32x4 k0 = *(const u32x4*)(Kbf + u0 * 16);
        u32x4 k1 = *(const u32x4*)(Kbf + u1 * 16);
        i32x8 kf = i32x8{(int)k0[0], (int)k0[1], (int)k0[2], (int)k0[3],
                         (int)k1[0], (int)k1[1], (int)k1[2], (int)k1[3]};
        sA = MFMAMX(kf, qf8[ks], sA);
      }
      __builtin_amdgcn_s_setprio(0);
      // ---- lean online softmax ----
      float g0 = max3f(sA[0], sA[1], sA[2]);
      float g1 = max3f(sA[3], sA[4], sA[5]);
      float g2 = max3f(sA[6], sA[7], sA[8]);
      float g3 = max3f(sA[9], sA[10], sA[11]);
      float g4 = max3f(sA[12], sA[13], sA[14]);
      float pmax_t = max3f(max3f(g0, g1, sA[15]), fmaxf(g2, g3), g4);
      pmax_t = fmaxf(pmax_t, __shfl_xor(pmax_t, 32));
      float pmax = pmax_t * cs;
      if (!__all(pmax - mrun <= 8.f)) {   // defer-max; 2^8=256 < fp8 max 448
        float mnew = fmaxf(mrun, pmax);
        float alpha = __builtin_exp2f(mrun - mnew);
#pragma unroll
        for (int i = 0; i < 8; ++i) oacc[i] *= alpha;
        lrun *= alpha;
        mrun = mnew;
      }
      float nm = -mrun;
      float sv[16], psum = 0.f;
#pragma unroll
      for (int r = 0; r < 16; ++r) {
        sv[r] = __builtin_exp2f(__builtin_fmaf(sA[r], cs, nm));
        psum += sv[r];
      }
      psum += __shfl_xor(psum, 32);
      lrun += psum;
      // ---- P -> fp8 B-frags: 8 cvt_pk_fp8 + 2 permlane32_swap ----
      uint Aw = (uint)__builtin_amdgcn_cvt_pk_fp8_f32(sv[0], sv[1], 0, false);
      Aw = (uint)__builtin_amdgcn_cvt_pk_fp8_f32(sv[2], sv[3], (int)Aw, true);
      uint Bw = (uint)__builtin_amdgcn_cvt_pk_fp8_f32(sv[4], sv[5], 0, false);
      Bw = (uint)__builtin_amdgcn_cvt_pk_fp8_f32(sv[6], sv[7], (int)Bw, true);
      uint Cw = (uint)__builtin_amdgcn_cvt_pk_fp8_f32(sv[8], sv[9], 0, false);
      Cw = (uint)__builtin_amdgcn_cvt_pk_fp8_f32(sv[10], sv[11], (int)Cw, true);
      uint Dw = (uint)__builtin_amdgcn_cvt_pk_fp8_f32(sv[12], sv[13], 0, false);
      Dw = (uint)__builtin_amdgcn_cvt_pk_fp8_f32(sv[14], sv[15], (int)Dw, true);
      asm("v_permlane32_swap_b32 %0, %1" : "+v"(Aw), "+v"(Bw));
      asm("v_permlane32_swap_b32 %0, %1" : "+v"(Cw), "+v"(Dw));
      long pf0 = __builtin_bit_cast(long, (u32x2){Aw, Bw});  // kv slots 0..15
      long pf1 = __builtin_bit_cast(long, (u32x2){Cw, Dw});  // kv slots 16..31
      // ---- PV: one b128 per d-block feeds both MFMAs ----
      __builtin_amdgcn_s_setprio(1);
#pragma unroll
      for (int db = 0; db < 8; ++db) {
        int L = (db * 32 + lq) * 2 + lh;
        int Pu = L ^ ((L >> 3) & 7);
        u32x4 vr = *(const u32x4*)(Vbf + Pu * 16);
        s64x2 vp = __builtin_bit_cast(s64x2, vr);
        oacc[db] = MFMAF8(vp[0], pf0, oacc[db]);
        oacc[db] = MFMAF8(vp[1], pf1, oacc[db]);
      }
      __builtin_amdgcn_s_setprio(0);
    }
    asm volatile("" ::: "memory");
    __builtin_amdgcn_s_barrier();
    asm volatile("" ::: "memory");
  }

  // ---- epilogue: raw partials -> LDS transpose (XOR-swz) -> coalesced store ----
  {
    uint* wregu = (uint*)Lf + w * 4096;   // 32 q-rows x 128 uints per wave
#pragma unroll
    for (int db = 0; db < 8; ++db)
#pragma unroll
      for (int rp = 0; rp < 8; ++rp) {
        int r0 = rp * 2;
        int d0 = db * 32 + (r0 & 3) + 8 * (r0 >> 2) + 4 * lh;
        uint pk;
        asm("v_cvt_pk_bf16_f32 %0, %1, %2"
            : "=v"(pk) : "v"(oacc[db][r0]), "v"(oacc[db][r0 + 1]));
        int idx = lq * 128 + (d0 >> 1);
        wregu[idx ^ ((lq & 7) << 2)] = pk;
      }
    if (lh == 0) {
      int idx = half * 32768 + bb * 4096 + qt * 128 + w * 32 + lq;
      mlbuf[idx] = mrun;                  // exp2-domain max
      mlbuf[65536 + idx] = lrun;
    }
  }
  __syncthreads();
  {
    int r = t >> 1;                        // 0..127 row in tile
    int wv2 = r >> 5, lqr = r & 31;
    const uint* basep = (const uint*)Lf + wv2 * 4096;
    ushort* pbase = half ? pb1 : pb0;
    ushort* dstr = pbase + ((size_t)bb * 4096 + qt * 128 + r) * 256 + (t & 1) * 128;
#pragma unroll
    for (int jj = 0; jj < 16; ++jj) {
      int ui = lqr * 128 + (t & 1) * 64 + jj * 4;
      u32x4 v = *(const u32x4*)(basep + (ui ^ ((lqr & 7) << 2)));
      *(u32x4*)(dstr + jj * 8) = v;
    }
  }
}

extern "C" void kernel_launch(void* const* d_in, const int* in_sizes, int n_in,
                              void* d_out, int out_size, void* d_ws, size_t ws_size,
                              hipStream_t stream) {
  const float* x   = (const float*)d_in[0];
  const float* gnw = (const float*)d_in[1];
  const float* gnb = (const float*)d_in[2];
  const float* wq  = (const float*)d_in[3];
  const float* bq  = (const float*)d_in[4];
  const float* wk  = (const float*)d_in[5];
  const float* bk  = (const float*)d_in[6];
  const float* wv  = (const float*)d_in[7];
  const float* bv  = (const float*)d_in[8];
  const float* wp  = (const float*)d_in[9];
  const float* bp  = (const float*)d_in[10];

  const size_t SEQ = 4096, CH = 256;
  const size_t MAT = SEQ * CH;
  char* ws = (char*)d_ws;
  const size_t BUF = 8 * MAT * 2;        // 16 MiB
  u8*     y8   = (u8*)(ws + 0 * BUF);    // fp8 y [b][n][c] (8 MB); slot reused by pb0
  u8*     qb8  = (u8*)(ws + 1 * BUF);    // fp8 q [b][n][c]  (8 MB)
  ushort* pb1  = (ushort*)(ws + 4 * BUF);
  ushort* pb0  = (ushort*)(ws + 0 * BUF); // y8 dead after QKV GEMM
  ushort* wpb  = (ushort*)(ws + 5 * BUF);        // bf16 wp (128 KB)
  u8*     wcat8 = (u8*)(wpb + 65536);            // fp8 [wq;wk;wv] (192 KB)
  float*  bcat   = (float*)(wcat8 + 196608);     // 768 floats
  float2* partial = (float2*)(bcat + 768);       // 512 float2 (4KB)
  float*  mlbuf  = (float*)(partial + 512);      // 131072 floats (512KB)

  gn_stats_cvt_kernel<<<576, 256, 0, stream>>>(x, partial, wq, wk, wv, wp,
                                               wcat8, wpb, bq, bk, bv, bcat);
  gn_apply_kernel<<<2048, 256, 0, stream>>>(x, partial, gnw, gnb, y8);

  // fused q|k|v GEMM (fp8 MX): outputs qb8 / kb8(+16MB) / vtb8(+32MB)
  gemm_qkv_kernel<<<dim3(192, 8), 256, 0, stream>>>(y8, wcat8, bcat, qb8);

  attn13_kernel<<<512, 256, 0, stream>>>(qb8, qb8 + 16777216, qb8 + 33554432,
                                         pb0, pb1, mlbuf);

  // proj GEMM with fused kv-half merge (no separate merge dispatch)
  gemm_proj_kernel<<<dim3(64, 8), 256, 0, stream>>>(wpb, pb0, pb1, mlbuf, bp,
                                                    x, (float*)d_out);
}

// Round 22
// 182.741 us; speedup vs baseline: 1.0360x; 1.0360x over previous
//
#include <hip/hip_runtime.h>

typedef __attribute__((ext_vector_type(8))) short s16x8;
typedef __attribute__((ext_vector_type(4))) float f32x4;
typedef __attribute__((ext_vector_type(16))) float f32x16;
typedef __attribute__((ext_vector_type(4))) uint u32x4;
typedef __attribute__((ext_vector_type(2))) uint u32x2;
typedef __attribute__((ext_vector_type(2))) long s64x2;
typedef __attribute__((ext_vector_type(8))) int i32x8;
typedef unsigned char u8;

#define MFMA16(a, b, c) __builtin_amdgcn_mfma_f32_16x16x32_bf16((a), (b), (c), 0, 0, 0)
#define MFMAF8(a, b, c) __builtin_amdgcn_mfma_f32_32x32x16_fp8_fp8((a), (b), (c), 0, 0, 0)
// MX-scaled fp8 K=64; fmt 0,0 = e4m3/e4m3; scale bytes 0x7F = e8m0 1.0
#define MFMAMX(a, b, c) \
  __builtin_amdgcn_mfma_scale_f32_32x32x64_f8f6f4((a), (b), (c), 0, 0, 0, 0x7F7F7F7F, 0, 0x7F7F7F7F)

__device__ __forceinline__ ushort f2bf(float f) {
  uint u = __builtin_bit_cast(uint, f);
  u = (u + 0x7fffu + ((u >> 16) & 1u)) >> 16;
  return (ushort)u;
}
__device__ __forceinline__ float max3f(float a, float b, float c) {
  return fmaxf(fmaxf(a, b), c);   // clang fuses to v_max3_f32
}

// ---------------- GN stats (512 blocks) + weight conversion (64 blocks) ----------
__global__ __launch_bounds__(256) void gn_stats_cvt_kernel(
    const float* __restrict__ x, float2* __restrict__ partial,
    const float* __restrict__ wq, const float* __restrict__ wk,
    const float* __restrict__ wv, const float* __restrict__ wp,
    u8* __restrict__ wcat8, ushort* __restrict__ wpb,
    const float* __restrict__ bq, const float* __restrict__ bk,
    const float* __restrict__ bv, float* __restrict__ bcat) {
  if (blockIdx.x >= 512) {
    int i = (blockIdx.x - 512) * 256 + threadIdx.x;  // [0,16384) float4
    const float4* s[3] = {(const float4*)wq, (const float4*)wk, (const float4*)wv};
#pragma unroll
    for (int m = 0; m < 3; ++m) {
      float4 v = s[m][i];
      uint u = (uint)__builtin_amdgcn_cvt_pk_fp8_f32(v.x, v.y, 0, false);
      u = (uint)__builtin_amdgcn_cvt_pk_fp8_f32(v.z, v.w, (int)u, true);
      ((uint*)wcat8)[m * 16384 + i] = u;
    }
    {
      float4 v = ((const float4*)wp)[i];
      uint lo = (uint)f2bf(v.x) | ((uint)f2bf(v.y) << 16);
      uint hi = (uint)f2bf(v.z) | ((uint)f2bf(v.w) << 16);
      *(uint2*)(wpb + (size_t)i * 4) = make_uint2(lo, hi);
    }
    if (blockIdx.x == 512) {
      int t = threadIdx.x;
      bcat[t] = bq[t];
      bcat[256 + t] = bk[t];
      bcat[512 + t] = bv[t];
    }
    return;
  }
  int bid = blockIdx.x;
  int b = bid >> 6, g = (bid >> 3) & 7, sl = bid & 7;
  const float4* src = (const float4*)(x + ((size_t)b * 256 + g * 32) * 4096) + sl * 4096;
  float s = 0.f, ss = 0.f;
#pragma unroll 4
  for (int i = threadIdx.x; i < 4096; i += 256) {
    float4 v = src[i];
    s += v.x + v.y + v.z + v.w;
    ss += v.x * v.x + v.y * v.y + v.z * v.z + v.w * v.w;
  }
#pragma unroll
  for (int off = 32; off; off >>= 1) {
    s += __shfl_down(s, off);
    ss += __shfl_down(ss, off);
  }
  __shared__ float ps[4], pss[4];
  int w = threadIdx.x >> 6, lane = threadIdx.x & 63;
  if (lane == 0) { ps[w] = s; pss[w] = ss; }
  __syncthreads();
  if (threadIdx.x == 0) {
    float2 r;
    r.x = ps[0] + ps[1] + ps[2] + ps[3];
    r.y = pss[0] + pss[1] + pss[2] + pss[3];
    partial[bid] = r;
  }
}

// ---------------- GN apply + transpose -> fp8 y (finalizes stats in-block) --------
__global__ __launch_bounds__(256) void gn_apply_kernel(
    const float* __restrict__ x, const float2* __restrict__ partial,
    const float* __restrict__ gw, const float* __restrict__ gb,
    u8* __restrict__ y8) {
  int bid = blockIdx.x;
  int b = bid >> 8;
  int rem = bid & 255;
  int ct = rem >> 6, nt = rem & 63;   // 64-channel tile = groups 2ct, 2ct+1
  int t = threadIdx.x;
  __shared__ float xs[64][65];
  __shared__ float smu2[2], srs2[2];
  if (t < 2) {
    float S = 0.f, SS = 0.f;
#pragma unroll
    for (int i = 0; i < 8; ++i) {
      float2 p = partial[(b << 6) | ((2 * ct + t) << 3) | i];
      S += p.x;
      SS += p.y;
    }
    float mu = S * (1.f / 131072.f);
    float var = SS * (1.f / 131072.f) - mu * mu;
    smu2[t] = mu;
    srs2[t] = rsqrtf(var + 1e-5f);
  }
  const float* xb = x + ((size_t)b * 256 + ct * 64) * 4096 + nt * 64;
  {
    int r = t >> 2, q = t & 3;
    const float4* src = (const float4*)(xb + (size_t)r * 4096 + q * 16);
#pragma unroll
    for (int i = 0; i < 4; ++i) {
      float4 v = src[i];
      xs[r][q * 16 + i * 4 + 0] = v.x;
      xs[r][q * 16 + i * 4 + 1] = v.y;
      xs[r][q * 16 + i * 4 + 2] = v.z;
      xs[r][q * 16 + i * 4 + 3] = v.w;
    }
  }
  __syncthreads();
  {
    int nr = t >> 2, q = t & 3;
    int c0 = q * 16;
    float vv[16];
#pragma unroll
    for (int i = 0; i < 16; ++i) {
      int ci = c0 + i;                  // 0..63 within tile
      int ch = ct * 64 + ci;
      int gsel = ci >> 5;
      float sc = gw[ch] * srs2[gsel];
      float sh = gb[ch] - smu2[gsel] * sc;
      vv[i] = xs[ci][nr] * sc + sh;
    }
    uint pw[4];
#pragma unroll
    for (int j = 0; j < 4; ++j) {
      uint u = (uint)__builtin_amdgcn_cvt_pk_fp8_f32(vv[4 * j], vv[4 * j + 1], 0, false);
      u = (uint)__builtin_amdgcn_cvt_pk_fp8_f32(vv[4 * j + 2], vv[4 * j + 3], (int)u, true);
      pw[j] = u;
    }
    u8* dst = y8 + ((size_t)(b * 4096 + nt * 64 + nr)) * 256 + ct * 64 + c0;
    u32x4 ov = {pw[0], pw[1], pw[2], pw[3]};
    *(u32x4*)dst = ov;
  }
}

// ---------------- QKV GEMM v4: fp8 MX, single-stage 64KB LDS, 2 blocks/CU --------
// C[4096][768] = y8 . wcat8^T + bcat; outputs routed to qb8/kb8/vtb8 (fp8).
__global__ __launch_bounds__(256) void gemm_qkv_kernel(
    const u8* __restrict__ A, const u8* __restrict__ B,
    const float* __restrict__ bias, u8* __restrict__ Cq) {
  int tm = blockIdx.x & 31, tn = blockIdx.x >> 5;   // 32 M-tiles x 6 N-tiles
  int bb = blockIdx.y;
  const u8* Ab = A + (size_t)bb * (4096 * 256) + (size_t)tm * 128 * 256;
  const u8* Bb = B + (size_t)tn * 128 * 256;

  __shared__ u8 As[32768];   // [128][256] fp8, XOR-swizzled (P = L ^ ((L>>4)&7))
  __shared__ u8 Bs[32768];

  int t = threadIdx.x, lane = t & 63, w = t >> 6;
  int wr = w >> 1, wc = w & 1, lq = lane & 31, lh = lane >> 5;

  f32x16 acc[2][2];
#pragma unroll
  for (int i = 0; i < 2; ++i)
#pragma unroll
    for (int j = 0; j < 2; ++j) acc[i][j] = (f32x16)(0.f);

  // stage full tiles: 8+8 DMA loads per thread
#pragma unroll
  for (int i = 0; i < 8; ++i) {
    int bu = i * 256 + w * 64;          // wave-uniform base unit (16B units)
    int Pu = bu + lane;                 // 0..2047
    int Lu = Pu ^ ((Pu >> 4) & 7);      // logical unit (same involution as attn K)
    int off = (Lu >> 4) * 256 + (Lu & 15) * 16;
    __builtin_amdgcn_global_load_lds(
        (const __attribute__((address_space(1))) uint*)(Ab + off),
        (__attribute__((address_space(3))) uint*)(As + bu * 16), 16, 0, 0);
    __builtin_amdgcn_global_load_lds(
        (const __attribute__((address_space(1))) uint*)(Bb + off),
        (__attribute__((address_space(3))) uint*)(Bs + bu * 16), 16, 0, 0);
  }
  asm volatile("s_waitcnt vmcnt(0)" ::: "memory");
  __builtin_amdgcn_s_barrier();

  // 16 MX MFMAs per wave (4 k-steps x 2x2 frags)
#pragma unroll
  for (int ks = 0; ks < 4; ++ks) {
    i32x8 af[2], bf[2];
#pragma unroll
    for (int mt = 0; mt < 2; ++mt) {
      int ra = wr * 64 + mt * 32 + lq;
      int u0 = (ks * 4 + lh * 2) ^ (ra & 7);
      int u1 = (ks * 4 + lh * 2 + 1) ^ (ra & 7);
      u32x4 lo = *(const u32x4*)(As + ra * 256 + u0 * 16);
      u32x4 hi = *(const u32x4*)(As + ra * 256 + u1 * 16);
      af[mt] = i32x8{(int)lo[0], (int)lo[1], (int)lo[2], (int)lo[3],
                     (int)hi[0], (int)hi[1], (int)hi[2], (int)hi[3]};
    }
#pragma unroll
    for (int nt = 0; nt < 2; ++nt) {
      int rb = wc * 64 + nt * 32 + lq;
      int u0 = (ks * 4 + lh * 2) ^ (rb & 7);
      int u1 = (ks * 4 + lh * 2 + 1) ^ (rb & 7);
      u32x4 lo = *(const u32x4*)(Bs + rb * 256 + u0 * 16);
      u32x4 hi = *(const u32x4*)(Bs + rb * 256 + u1 * 16);
      bf[nt] = i32x8{(int)lo[0], (int)lo[1], (int)lo[2], (int)lo[3],
                     (int)hi[0], (int)hi[1], (int)hi[2], (int)hi[3]};
    }
#pragma unroll
    for (int mt = 0; mt < 2; ++mt)
#pragma unroll
      for (int nt = 0; nt < 2; ++nt)
        acc[mt][nt] = MFMAMX(af[mt], bf[nt], acc[mt][nt]);
  }

  // epilogue: route fp8 bytes to qb8 / kb8(+16MB) / vtb8(+32MB, kv-perm on row)
  u8* Cb = Cq + (size_t)bb * (4096 * 256);
#pragma unroll
  for (int mt = 0; mt < 2; ++mt) {
#pragma unroll
    for (int nt = 0; nt < 2; ++nt) {
#pragma unroll
      for (int r = 0; r < 16; ++r) {
        int row = tm * 128 + wr * 64 + mt * 32 + (r & 3) + 8 * (r >> 2) + 4 * lh;
        int col = tn * 128 + wc * 64 + nt * 32 + lq;
        float v = acc[mt][nt][r] + bias[col];
        uint pk8 = (uint)__builtin_amdgcn_cvt_pk_fp8_f32(v, v, 0, false);
        if (col < 512) {
          u8* C = Cb + ((col >= 256) ? 16777216 : 0);
          C[(size_t)row * 256 + (col & 255)] = (u8)(pk8 & 0xff);
        } else {
          int rr = row & 31;
          int pr = (row & ~31) |
                   ((rr & 7) | (((rr >> 4) & 1) << 3) | (((rr >> 3) & 1) << 4));
          u8* C = Cb + 33554432;
          C[(size_t)(col - 512) * 4096 + pr] = (u8)(pk8 & 0xff);
        }
      }
    }
  }
}

// ---------------- proj GEMM with fused kv-half merge ----------------
__global__ __launch_bounds__(256) void gemm_proj_kernel(
    const ushort* __restrict__ A, const ushort* __restrict__ P0,
    const ushort* __restrict__ P1, const float* __restrict__ mlb,
    const float* __restrict__ bias, const float* __restrict__ resid,
    float* __restrict__ Cout) {
  const size_t MAT = 4096 * 256;
  int tm = blockIdx.x & 1, tn = blockIdx.x >> 1;   // 2 x 32 tiles
  int bb = blockIdx.y;
  const ushort* Ab = A + (size_t)tm * 128 * 256;
  const ushort* P0b = P0 + (size_t)bb * MAT + (size_t)tn * 128 * 256;
  const ushort* P1b = P1 + (size_t)bb * MAT + (size_t)tn * 128 * 256;
  const int mlbase = bb * 4096 + tn * 128;

  __shared__ ushort As[2][8192];
  __shared__ ushort Bs[2][8192];

  int t = threadIdx.x, lane = t & 63, w = t >> 6;
  int wr = w >> 1, wc = w & 1, lq = lane & 15, lg = lane >> 4;

  f32x4 acc[4][4];
#pragma unroll
  for (int i = 0; i < 4; ++i)
#pragma unroll
    for (int j = 0; j < 4; ++j) acc[i][j] = f32x4{0.f, 0.f, 0.f, 0.f};

  u32x4 rb0[4], rb1[4];
  float rw0[4], rw1[4];

  auto issueA = [&](int kb, int db) {
#pragma unroll
    for (int i = 0; i < 4; ++i) {
      int bu = i * 256 + w * 64;
      int u = bu + lane;
      int row = u >> 3, c = u & 7;
      int cl = c ^ (row & 7);
      const ushort* sa = Ab + (size_t)row * 256 + kb * 64 + cl * 8;
      __builtin_amdgcn_global_load_lds(
          (const __attribute__((address_space(1))) uint*)sa,
          (__attribute__((address_space(3))) uint*)(&As[db][0] + bu * 8), 16, 0, 0);
    }
  };
  auto loadB = [&](int kb) {
#pragma unroll
    for (int i = 0; i < 4; ++i) {
      int bu = i * 256 + w * 64;
      int u = bu + lane;
      int row = u >> 3, c = u & 7;
      int cl = c ^ (row & 7);
      rb0[i] = *(const u32x4*)(P0b + (size_t)row * 256 + kb * 64 + cl * 8);
      rb1[i] = *(const u32x4*)(P1b + (size_t)row * 256 + kb * 64 + cl * 8);
      int gr = mlbase + row;
      float m0 = mlb[gr], m1 = mlb[32768 + gr];
      float l0 = mlb[65536 + gr], l1 = mlb[98304 + gr];
      float M = fmaxf(m0, m1);
      float e0 = __builtin_exp2f(m0 - M), e1 = __builtin_exp2f(m1 - M);
      float inv = 1.f / (l0 * e0 + l1 * e1);
      rw0[i] = e0 * inv;
      rw1[i] = e1 * inv;
    }
  };
  auto writeB = [&](int db) {
#pragma unroll
    for (int i = 0; i < 4; ++i) {
      int bu = i * 256 + w * 64;
      uint outw[4];
#pragma unroll
      for (int j = 0; j < 4; ++j) {
        float alo = __builtin_bit_cast(float, rb0[i][j] << 16);
        float ahi = __builtin_bit_cast(float, rb0[i][j] & 0xffff0000u);
        float blo = __builtin_bit_cast(float, rb1[i][j] << 16);
        float bhi = __builtin_bit_cast(float, rb1[i][j] & 0xffff0000u);
        float flo = alo * rw0[i] + blo * rw1[i];
        float fhi = ahi * rw0[i] + bhi * rw1[i];
        asm("v_cvt_pk_bf16_f32 %0, %1, %2" : "=v"(outw[j]) : "v"(flo), "v"(fhi));
      }
      u32x4 ov = {outw[0], outw[1], outw[2], outw[3]};
      *(u32x4*)&Bs[db][(size_t)(bu + lane) * 8] = ov;
    }
  };

  issueA(0, 0);
  loadB(0);
  writeB(0);
  asm volatile("s_waitcnt vmcnt(0) lgkmcnt(0)" ::: "memory");
  __builtin_amdgcn_s_barrier();

#pragma unroll
  for (int kb = 0; kb < 4; ++kb) {
    const int db = kb & 1;
    if (kb < 3) {
      issueA(kb + 1, db ^ 1);
      loadB(kb + 1);                    // loads in flight across compute
    }
    const ushort* Abf = &As[db][0];
    const ushort* Bbf = &Bs[db][0];
#pragma unroll
    for (int ks = 0; ks < 2; ++ks) {
      s16x8 af[4], bf[4];
#pragma unroll
      for (int mt = 0; mt < 4; ++mt) {
        int row = wr * 64 + mt * 16 + lq;
        af[mt] = *(const s16x8*)&Abf[row * 64 + (((ks * 4 + lg) ^ (row & 7)) << 3)];
      }
#pragma unroll
      for (int nt = 0; nt < 4; ++nt) {
        int row = wc * 64 + nt * 16 + lq;
        bf[nt] = *(const s16x8*)&Bbf[row * 64 + (((ks * 4 + lg) ^ (row & 7)) << 3)];
      }
#pragma unroll
      for (int mt = 0; mt < 4; ++mt)
#pragma unroll
        for (int nt = 0; nt < 4; ++nt)
          acc[mt][nt] = MFMA16(af[mt], bf[nt], acc[mt][nt]);
    }
    if (kb < 3) writeB(db ^ 1);
    asm volatile("s_waitcnt vmcnt(0) lgkmcnt(0)" ::: "memory");
    __builtin_amdgcn_s_barrier();
  }

  int mBase = tm * 128 + wr * 64;
  int nBase = tn * 128 + wc * 64;
#pragma unroll
  for (int mt = 0; mt < 4; ++mt) {
#pragma unroll
    for (int nt = 0; nt < 4; ++nt) {
#pragma unroll
      for (int r = 0; r < 4; ++r) {
        int row = mBase + mt * 16 + lg * 4 + r;
        int col = nBase + nt * 16 + lq;
        size_t idx = (size_t)bb * MAT + (size_t)row * 4096 + col;
        Cout[idx] = acc[mt][nt][r] + bias[row] + resid[idx];
      }
    }
  }
}

// ---------------- Flash attention v12: MX QK single-chain, fp8 PV ----------------
// Grid 512 = 8 batch x 32 qtiles(128 rows) x 2 kv-halves; 256 thr = 4 waves.
__global__ __launch_bounds__(256, 2) void attn12_kernel(
    const u8* __restrict__ q, const u8* __restrict__ k,
    const u8* __restrict__ vT, ushort* __restrict__ pb0,
    ushort* __restrict__ pb1, float* __restrict__ mlbuf) {
  const int bb = blockIdx.x & 7;          // batch -> XCD pinning
  const int rem = blockIdx.x >> 3;        // 0..63
  const int qt = rem & 31;                // 32 qtiles x 128 rows
  const int half = rem >> 5;              // kv half
  const int t = threadIdx.x, w = t >> 6, lane = t & 63;
  const int lq = lane & 31, lh = lane >> 5;

  __shared__ u8 Lf[65536];   // main loop: 2 bufs x (K 8KB + V 8KB) = 32KB; epilogue 64KB

  const u8* kb = k + (size_t)bb * (4096 * 256);
  const u8* vb = vT + (size_t)bb * (4096 * 256);

  // Q fragments for MX QK: frag ks holds channels ks*64 + lh*32 .. +31 (32B)
  const int qrow = bb * 4096 + qt * 128 + w * 32 + lq;
  i32x8 qf8[4];
  {
    const u8* qp = q + (size_t)qrow * 256 + lh * 32;
#pragma unroll
    for (int ks = 0; ks < 4; ++ks) {
      u32x4 lo = *(const u32x4*)(qp + ks * 64);
      u32x4 hi = *(const u32x4*)(qp + ks * 64 + 16);
      qf8[ks] = i32x8{(int)lo[0], (int)lo[1], (int)lo[2], (int)lo[3],
                      (int)hi[0], (int)hi[1], (int)hi[2], (int)hi[3]};
    }
  }
  f32x16 oacc[8];
#pragma unroll
  for (int i = 0; i < 8; ++i) oacc[i] = (f32x16)(0.f);
  float mrun = -3e38f, lrun = 0.f;        // exp2 (log2) domain
  const float cs = 0.0625f * 1.44269504f; // scale * log2(e)

  // stage one 32-row chunk (16KB) into buffer db; 4 gload_lds per thread
  auto stage = [&](int it, int db) {
    const int ci = half * 64 + it;
    const u8* kcb = kb + (size_t)ci * (32 * 256);
    const u8* vcb = vb + (size_t)ci * 32;
    u8* base = Lf + db * 16384;
#pragma unroll
    for (int i = 0; i < 2; ++i) {
      int bu = w * 128 + i * 64;          // wave-uniform base unit (16B units)
      int Pu = bu + lane;
      {  // K region: logical L = row*16 + off16; P = L ^ ((L>>4)&7)
        int Lu = Pu ^ ((Pu >> 4) & 7);
        const u8* ksrc = kcb + (Lu >> 4) * 256 + (Lu & 15) * 16;
        __builtin_amdgcn_global_load_lds(
            (const __attribute__((address_space(1))) uint*)ksrc,
            (__attribute__((address_space(3))) uint*)(base + bu * 16), 16, 0, 0);
      }
      {  // V region: logical L = drow*2 + lhv; P = L ^ ((L>>3)&7)
        int Lu = Pu ^ ((Pu >> 3) & 7);
        const u8* vsrc = vcb + (size_t)(Lu >> 1) * 4096 + (Lu & 1) * 16;
        __builtin_amdgcn_global_load_lds(
            (const __attribute__((address_space(1))) uint*)vsrc,
            (__attribute__((address_space(3))) uint*)(base + 8192 + bu * 16), 16, 0, 0);
      }
    }
  };

  stage(0, 0);

#pragma unroll 1
  for (int j = 0; j < 64; ++j) {
    if (j < 63) {
      stage(j + 1, (j + 1) & 1);
      asm volatile("s_waitcnt vmcnt(4)" ::: "memory");
    } else {
      asm volatile("s_waitcnt vmcnt(0)" ::: "memory");
    }
    __builtin_amdgcn_s_barrier();

    const u8* Kbf = Lf + (j & 1) * 16384;
    const u8* Vbf = Kbf + 8192;

    // ---- QK^T: 4 MX-scaled MFMAs (K=64 each), single chain (issue-covered) ----
    __builtin_amdgcn_s_setprio(1);
    f32x16 sA = (f32x16)(0.f);
#pragma unroll
    for (int ks = 0; ks < 4; ++ks) {
      int u0 = (lq * 16 + ks * 4 + lh * 2) ^ (lq & 7);
      int u1 = (lq * 16 + ks * 4 + lh * 2 + 1) ^ (lq & 7);
      u32x4 k0 = *(const u32x4*)(Kbf + u0 * 16);
      u32x4 k1 = *(const u32x4*)(Kbf + u1 * 16);
      i32x8 kf = i32x8{(int)k0[0], (int)k0[1], (int)k0[2], (int)k0[3],
                       (int)k1[0], (int)k1[1], (int)k1[2], (int)k1[3]};
      sA = MFMAMX(kf, qf8[ks], sA);
    }
    __builtin_amdgcn_s_setprio(0);
    // ---- lean online softmax: max on raw sums (1 mul), fma+exp2 fused ----
    float g0 = max3f(sA[0], sA[1], sA[2]);
    float g1 = max3f(sA[3], sA[4], sA[5]);
    float g2 = max3f(sA[6], sA[7], sA[8]);
    float g3 = max3f(sA[9], sA[10], sA[11]);
    float g4 = max3f(sA[12], sA[13], sA[14]);
    float pmax_t = max3f(max3f(g0, g1, sA[15]), fmaxf(g2, g3), g4);
    pmax_t = fmaxf(pmax_t, __shfl_xor(pmax_t, 32));
    float pmax = pmax_t * cs;
    if (!__all(pmax - mrun <= 8.f)) {     // defer-max; 2^8=256 < fp8 max 448
      float mnew = fmaxf(mrun, pmax);
      float alpha = __builtin_exp2f(mrun - mnew);
#pragma unroll
      for (int i = 0; i < 8; ++i) oacc[i] *= alpha;
      lrun *= alpha;
      mrun = mnew;
    }
    float nm = -mrun;
    float sv[16], psum = 0.f;
#pragma unroll
    for (int r = 0; r < 16; ++r) {
      sv[r] = __builtin_exp2f(__builtin_fmaf(sA[r], cs, nm));
      psum += sv[r];
    }
    psum += __shfl_xor(psum, 32);
    lrun += psum;
    // ---- P -> fp8 B-frags: 8 cvt_pk_fp8 + 2 permlane32_swap ----
    uint Aw = (uint)__builtin_amdgcn_cvt_pk_fp8_f32(sv[0], sv[1], 0, false);
    Aw = (uint)__builtin_amdgcn_cvt_pk_fp8_f32(sv[2], sv[3], (int)Aw, true);
    uint Bw = (uint)__builtin_amdgcn_cvt_pk_fp8_f32(sv[4], sv[5], 0, false);
    Bw = (uint)__builtin_amdgcn_cvt_pk_fp8_f32(sv[6], sv[7], (int)Bw, true);
    uint Cw = (uint)__builtin_amdgcn_cvt_pk_fp8_f32(sv[8], sv[9], 0, false);
    Cw = (uint)__builtin_amdgcn_cvt_pk_fp8_f32(sv[10], sv[11], (int)Cw, true);
    uint Dw = (uint)__builtin_amdgcn_cvt_pk_fp8_f32(sv[12], sv[13], 0, false);
    Dw = (uint)__builtin_amdgcn_cvt_pk_fp8_f32(sv[14], sv[15], (int)Dw, true);
    asm("v_permlane32_swap_b32 %0, %1" : "+v"(Aw), "+v"(Bw));
    asm("v_permlane32_swap_b32 %0, %1" : "+v"(Cw), "+v"(Dw));
    long pf0 = __builtin_bit_cast(long, (u32x2){Aw, Bw});  // kv slots 0..15
    long pf1 = __builtin_bit_cast(long, (u32x2){Cw, Dw});  // kv slots 16..31
    // ---- PV: one b128 per d-block feeds both MFMAs ----
    __builtin_amdgcn_s_setprio(1);
#pragma unroll
    for (int db = 0; db < 8; ++db) {
      int L = (db * 32 + lq) * 2 + lh;
      int Pu = L ^ ((L >> 3) & 7);
      u32x4 vr = *(const u32x4*)(Vbf + Pu * 16);
      s64x2 vp = __builtin_bit_cast(s64x2, vr);
      oacc[db] = MFMAF8(vp[0], pf0, oacc[db]);
      oacc[db] = MFMAF8(vp[1], pf1, oacc[db]);
    }
    __builtin_amdgcn_s_setprio(0);
    asm volatile("" ::: "memory");
    __builtin_amdgcn_s_barrier();
    asm volatile("" ::: "memory");
  }

  // ---- epilogue: raw partials -> LDS transpose (XOR-swz) -> coalesced store ----
  {
    uint* wregu = (uint*)Lf + w * 4096;   // 32 q-rows x 128 uints per wave
#pragma unroll
    for (int db = 0; db < 8; ++db)
#pragma unroll
      for (int rp = 0; rp < 8; ++rp) {
        int r0 = rp * 2;
        int d0 = db * 32 + (r0 & 3) + 8 * (r0 >> 2) + 4 * lh;
        uint pk;
        asm("v_cvt_pk_bf16_f32 %0, %1, %2"
            : "=v"(pk) : "v"(oacc[db][r0]), "v"(oacc[db][r0 + 1]));
        int idx = lq * 128 + (d0 >> 1);
        wregu[idx ^ ((lq & 7) << 2)] = pk;
      }
    if (lh == 0) {
      int idx = half * 32768 + bb * 4096 + qt * 128 + w * 32 + lq;
      mlbuf[idx] = mrun;                  // exp2-domain max
      mlbuf[65536 + idx] = lrun;
    }
  }
  __syncthreads();
  {
    int r = t >> 1;                        // 0..127 row in tile
    int wv2 = r >> 5, lqr = r & 31;
    const uint* basep = (const uint*)Lf + wv2 * 4096;
    ushort* pbase = half ? pb1 : pb0;
    ushort* dstr = pbase + ((size_t)bb * 4096 + qt * 128 + r) * 256 + (t & 1) * 128;
#pragma unroll
    for (int jj = 0; jj < 16; ++jj) {
      int ui = lqr * 128 + (t & 1) * 64 + jj * 4;
      u32x4 v = *(const u32x4*)(basep + (ui ^ ((lqr & 7) << 2)));
      *(u32x4*)(dstr + jj * 8) = v;
    }
  }
}

extern "C" void kernel_launch(void* const* d_in, const int* in_sizes, int n_in,
                              void* d_out, int out_size, void* d_ws, size_t ws_size,
                              hipStream_t stream) {
  const float* x   = (const float*)d_in[0];
  const float* gnw = (const float*)d_in[1];
  const float* gnb = (const float*)d_in[2];
  const float* wq  = (const float*)d_in[3];
  const float* bq  = (const float*)d_in[4];
  const float* wk  = (const float*)d_in[5];
  const float* bk  = (const float*)d_in[6];
  const float* wv  = (const float*)d_in[7];
  const float* bv  = (const float*)d_in[8];
  const float* wp  = (const float*)d_in[9];
  const float* bp  = (const float*)d_in[10];

  const size_t SEQ = 4096, CH = 256;
  const size_t MAT = SEQ * CH;
  char* ws = (char*)d_ws;
  const size_t BUF = 8 * MAT * 2;        // 16 MiB
  u8*     y8   = (u8*)(ws + 0 * BUF);    // fp8 y [b][n][c] (8 MB); slot reused by pb0
  u8*     qb8  = (u8*)(ws + 1 * BUF);    // fp8 q [b][n][c]  (8 MB)
  ushort* pb1  = (ushort*)(ws + 4 * BUF);
  ushort* pb0  = (ushort*)(ws + 0 * BUF); // y8 dead after QKV GEMM
  ushort* wpb  = (ushort*)(ws + 5 * BUF);        // bf16 wp (128 KB)
  u8*     wcat8 = (u8*)(wpb + 65536);            // fp8 [wq;wk;wv] (192 KB)
  float*  bcat   = (float*)(wcat8 + 196608);     // 768 floats
  float2* partial = (float2*)(bcat + 768);       // 512 float2 (4KB)
  float*  mlbuf  = (float*)(partial + 512);      // 131072 floats (512KB)

  gn_stats_cvt_kernel<<<576, 256, 0, stream>>>(x, partial, wq, wk, wv, wp,
                                               wcat8, wpb, bq, bk, bv, bcat);
  gn_apply_kernel<<<2048, 256, 0, stream>>>(x, partial, gnw, gnb, y8);

  // fused q|k|v GEMM (fp8 MX): outputs qb8 / kb8(+16MB) / vtb8(+32MB)
  gemm_qkv_kernel<<<dim3(192, 8), 256, 0, stream>>>(y8, wcat8, bcat, qb8);

  attn12_kernel<<<512, 256, 0, stream>>>(qb8, qb8 + 16777216, qb8 + 33554432,
                                         pb0, pb1, mlbuf);

  // proj GEMM with fused kv-half merge (no separate merge dispatch)
  gemm_proj_kernel<<<dim3(64, 8), 256, 0, stream>>>(wpb, pb0, pb1, mlbuf, bp,
                                                    x, (float*)d_out);
}